// Round 1
// baseline (264.661 us; speedup 1.0000x reference)
//
#include <hip/hip_runtime.h>
#include <hip/hip_bf16.h>
#include <stdint.h>

#define HIDDEN 128

// round-to-nearest-even f32 -> bf16 bits
static __device__ __forceinline__ unsigned short f2bf(float f) {
    union { float f; uint32_t u; } v; v.f = f;
    uint32_t u = v.u;
    uint32_t r = (u + 0x7fffu + ((u >> 16) & 1u)) >> 16;
    return (unsigned short)r;
}
static __device__ __forceinline__ float bf_lo(uint32_t p) {  // element 2i (low 16 bits)
    union { uint32_t u; float f; } v; v.u = p << 16; return v.f;
}
static __device__ __forceinline__ float bf_hi(uint32_t p) {  // element 2i+1 (high 16 bits)
    union { uint32_t u; float f; } v; v.u = p & 0xffff0000u; return v.f;
}

// UV[n][o]: o<128 -> u_o = sum_k z[n][k]*W1[k][o]
//           o>=128 -> v_{o-128} = sum_k z[n][k]*W1[128+k][o-128]
// One wave handles 8 nodes. Lane l owns 4 consecutive outputs:
//   half = l>=32 (u vs v half), col = (l&31)*4.
__global__ __launch_bounds__(256) void precompute_uv(
    const float* __restrict__ z, const float* __restrict__ W1,
    unsigned short* __restrict__ UV, int n_nodes)
{
    const int lane = threadIdx.x & 63;
    const int wave = threadIdx.x >> 6;
    const int n0 = (blockIdx.x * 4 + wave) * 8;
    if (n0 >= n_nodes) return;

    const int half = lane >> 5;           // 0: u-half, 1: v-half
    const int col  = (lane & 31) * 4;     // output col within half, [0,128)
    const float* __restrict__ w1p = W1 + (size_t)(half * 128) * 128 + col;

    const float* zp[8];
    int nid[8];
    #pragma unroll
    for (int i = 0; i < 8; ++i) {
        int n = n0 + i;
        nid[i] = (n < n_nodes) ? n : (n_nodes - 1);
        zp[i] = z + (size_t)nid[i] * HIDDEN;
    }

    float acc[8][4];
    #pragma unroll
    for (int i = 0; i < 8; ++i)
        acc[i][0] = acc[i][1] = acc[i][2] = acc[i][3] = 0.f;

    for (int k = 0; k < HIDDEN; k += 4) {
        float4 zk[8];
        #pragma unroll
        for (int i = 0; i < 8; ++i)
            zk[i] = *reinterpret_cast<const float4*>(zp[i] + k);
        #pragma unroll
        for (int kk = 0; kk < 4; ++kk) {
            const float4 w = *reinterpret_cast<const float4*>(w1p + (size_t)(k + kk) * 128);
            #pragma unroll
            for (int i = 0; i < 8; ++i) {
                const float zs = (&zk[i].x)[kk];
                acc[i][0] = fmaf(zs, w.x, acc[i][0]);
                acc[i][1] = fmaf(zs, w.y, acc[i][1]);
                acc[i][2] = fmaf(zs, w.z, acc[i][2]);
                acc[i][3] = fmaf(zs, w.w, acc[i][3]);
            }
        }
    }

    #pragma unroll
    for (int i = 0; i < 8; ++i) {
        const int n = n0 + i;
        if (n >= n_nodes) break;
        ushort4 s;
        s.x = f2bf(acc[i][0]); s.y = f2bf(acc[i][1]);
        s.z = f2bf(acc[i][2]); s.w = f2bf(acc[i][3]);
        *reinterpret_cast<ushort4*>(UV + (size_t)n * 256 + half * 128 + col) = s;
    }
}

// 16 lanes per edge. Lane q owns elements [q*8, q*8+8).
// score[e] = sum_j relu(u[src][j] + v[dst][j] + b1[j]) * W2[j] + b2
__global__ __launch_bounds__(256) void edge_score(
    const int* __restrict__ ei, const unsigned short* __restrict__ UV,
    const float* __restrict__ b1, const float* __restrict__ W2,
    const float* __restrict__ b2, float* __restrict__ out, int n_edges)
{
    const int tid = blockIdx.x * 256 + threadIdx.x;
    const int e = tid >> 4;
    if (e >= n_edges) return;
    const int q = threadIdx.x & 15;

    const int src = ei[e];
    const int dst = ei[n_edges + e];

    const uint4 uraw = *reinterpret_cast<const uint4*>(UV + (size_t)src * 256 + q * 8);
    const uint4 vraw = *reinterpret_cast<const uint4*>(UV + (size_t)dst * 256 + 128 + q * 8);
    const float4 b1a = *reinterpret_cast<const float4*>(b1 + q * 8);
    const float4 b1b = *reinterpret_cast<const float4*>(b1 + q * 8 + 4);
    const float4 w2a = *reinterpret_cast<const float4*>(W2 + q * 8);
    const float4 w2b = *reinterpret_cast<const float4*>(W2 + q * 8 + 4);

    const uint32_t up[4] = { uraw.x, uraw.y, uraw.z, uraw.w };
    const uint32_t vp[4] = { vraw.x, vraw.y, vraw.z, vraw.w };
    const float bb[8] = { b1a.x, b1a.y, b1a.z, b1a.w, b1b.x, b1b.y, b1b.z, b1b.w };
    const float ww[8] = { w2a.x, w2a.y, w2a.z, w2a.w, w2b.x, w2b.y, w2b.z, w2b.w };

    float sum = 0.f;
    #pragma unroll
    for (int p = 0; p < 4; ++p) {
        float h0 = bf_lo(up[p]) + bf_lo(vp[p]) + bb[2 * p];
        float h1 = bf_hi(up[p]) + bf_hi(vp[p]) + bb[2 * p + 1];
        h0 = fmaxf(h0, 0.f);
        h1 = fmaxf(h1, 0.f);
        sum = fmaf(h0, ww[2 * p], sum);
        sum = fmaf(h1, ww[2 * p + 1], sum);
    }
    // note: lane q owns elems q*8..q*8+7 => pairs are (2p, 2p+1) within the
    // 8-element slice; bb/ww above are indexed with the same local order.
    // wait -- slice has 8 elems = 4 uint pairs; local elem idx = 2p,2p+1. OK.

    // reduce across the 16-lane group
    sum += __shfl_xor(sum, 1, 64);
    sum += __shfl_xor(sum, 2, 64);
    sum += __shfl_xor(sum, 4, 64);
    sum += __shfl_xor(sum, 8, 64);

    if (q == 0) out[e] = sum + b2[0];
}

extern "C" void kernel_launch(void* const* d_in, const int* in_sizes, int n_in,
                              void* d_out, int out_size, void* d_ws, size_t ws_size,
                              hipStream_t stream) {
    const float* z  = (const float*)d_in[0];
    const int*   ei = (const int*)d_in[1];
    const float* W1 = (const float*)d_in[2];
    const float* b1 = (const float*)d_in[3];
    const float* W2 = (const float*)d_in[4];
    const float* b2 = (const float*)d_in[5];
    float* out = (float*)d_out;

    const int n_nodes = in_sizes[0] / HIDDEN;
    const int n_edges = in_sizes[1] / 2;

    unsigned short* UV = (unsigned short*)d_ws;  // [n_nodes][256] bf16

    // Kernel 1: per-node u/v precompute (32 nodes per 256-thread block)
    {
        int blocks = (n_nodes + 31) / 32;
        precompute_uv<<<blocks, 256, 0, stream>>>(z, W1, UV, n_nodes);
    }
    // Kernel 2: per-edge score (16 edges per 256-thread block)
    {
        int blocks = (n_edges * 16 + 255) / 256;
        edge_score<<<blocks, 256, 0, stream>>>(ei, UV, b1, W2, b2, out, n_edges);
    }
}

// Round 2
// 182.776 us; speedup vs baseline: 1.4480x; 1.4480x over previous
//
#include <hip/hip_runtime.h>
#include <hip/hip_bf16.h>
#include <stdint.h>

#define HIDDEN 128

typedef __attribute__((ext_vector_type(8))) short bf16x8;
typedef __attribute__((ext_vector_type(4))) float f32x4;

// round-to-nearest-even f32 -> bf16 bits
static __device__ __forceinline__ unsigned short f2bf(float f) {
    union { float f; uint32_t u; } v; v.f = f;
    uint32_t u = v.u;
    uint32_t r = (u + 0x7fffu + ((u >> 16) & 1u)) >> 16;
    return (unsigned short)r;
}
static __device__ __forceinline__ float bf_lo(uint32_t p) {
    union { uint32_t u; float f; } v; v.u = p << 16; return v.f;
}
static __device__ __forceinline__ float bf_hi(uint32_t p) {
    union { uint32_t u; float f; } v; v.u = p & 0xffff0000u; return v.f;
}

static __device__ __forceinline__ bf16x8 pack8(float4 a, float4 b) {
    bf16x8 r;
    r[0] = (short)f2bf(a.x); r[1] = (short)f2bf(a.y);
    r[2] = (short)f2bf(a.z); r[3] = (short)f2bf(a.w);
    r[4] = (short)f2bf(b.x); r[5] = (short)f2bf(b.y);
    r[6] = (short)f2bf(b.z); r[7] = (short)f2bf(b.w);
    return r;
}

// MFMA GEMM: UV[n][c] = sum_k z[n][k] * B[k][c]
//   B[k][c] = W1[k + 128*(c>=128)][c & 127]
// B staged in LDS column-major: Blds[c][128 k], bf16, XOR-swizzled:
//   element index within column = k ^ ((c & 15) << 3)
// Each block: 4 waves, each wave one 16-row M-subtile of a 64-row tile,
// all 256 N-cols (16 N-subtiles x 4 K-subtiles of 16x16x32 MFMA).
__global__ __launch_bounds__(256, 2) void precompute_mfma(
    const float* __restrict__ z, const float* __restrict__ W1,
    unsigned short* __restrict__ UV, int n_nodes, int n_tiles)
{
    __shared__ unsigned short Blds[256 * 128];  // 64 KB

    const int tid = threadIdx.x;

    // ---- stage B (fp32 W1 -> bf16, swizzled) ----
    // chunk cid: r2 = cid & 127 (row pair 2*r2, 2*r2+1 of W1), j4 = cid >> 7 (col group)
    // consecutive lanes -> consecutive r2 -> k varies -> LDS banks spread
    for (int cid = tid; cid < 4096; cid += 256) {
        const int r2 = cid & 127;
        const int j4 = cid >> 7;
        const int r = r2 * 2;
        const float4 w0 = *reinterpret_cast<const float4*>(W1 + (size_t)r * 128 + j4 * 4);
        const float4 w1r = *reinterpret_cast<const float4*>(W1 + (size_t)(r + 1) * 128 + j4 * 4);
        const int k = r & 127;                       // even
        const int chalf = (r >= 128) ? 128 : 0;
        #pragma unroll
        for (int cc = 0; cc < 4; ++cc) {
            const int c = chalf + j4 * 4 + cc;
            const uint32_t lo = f2bf((&w0.x)[cc]);
            const uint32_t hi = f2bf((&w1r.x)[cc]);
            const uint32_t packed = lo | (hi << 16);
            const int idx = c * 128 + (k ^ ((c & 15) << 3));
            *reinterpret_cast<uint32_t*>(&Blds[idx]) = packed;
        }
    }
    __syncthreads();

    const int lane = tid & 63;
    const int wv = tid >> 6;
    const int lg = lane >> 4;   // lane group 0..3 (k-block)
    const int lr = lane & 15;   // row (A) / col (B) within subtile

    const int stride_tiles = gridDim.x;
    int tile = blockIdx.x;
    if (tile >= n_tiles) return;

    // prefetch A for first tile
    float4 cur[8];
    {
        int row = tile * 64 + wv * 16 + lr;
        row = (row < n_nodes) ? row : (n_nodes - 1);
        const float* zrow = z + (size_t)row * HIDDEN;
        #pragma unroll
        for (int ks = 0; ks < 4; ++ks) {
            cur[2 * ks]     = *reinterpret_cast<const float4*>(zrow + ks * 32 + lg * 8);
            cur[2 * ks + 1] = *reinterpret_cast<const float4*>(zrow + ks * 32 + lg * 8 + 4);
        }
    }

    while (tile < n_tiles) {
        const int next = tile + stride_tiles;
        // issue next tile's A loads (clamped; wasted-but-safe on last iter)
        float4 nxt[8];
        {
            int row = next * 64 + wv * 16 + lr;
            row = (row < n_nodes) ? row : (n_nodes - 1);
            const float* zrow = z + (size_t)row * HIDDEN;
            #pragma unroll
            for (int ks = 0; ks < 4; ++ks) {
                nxt[2 * ks]     = *reinterpret_cast<const float4*>(zrow + ks * 32 + lg * 8);
                nxt[2 * ks + 1] = *reinterpret_cast<const float4*>(zrow + ks * 32 + lg * 8 + 4);
            }
        }

        // convert current A to bf16 fragments
        bf16x8 afr[4];
        #pragma unroll
        for (int ks = 0; ks < 4; ++ks)
            afr[ks] = pack8(cur[2 * ks], cur[2 * ks + 1]);

        // MFMA: 16 N-subtiles x 4 K-subtiles
        f32x4 acc[16];
        #pragma unroll
        for (int ns = 0; ns < 16; ++ns) {
            acc[ns] = (f32x4){0.f, 0.f, 0.f, 0.f};
            const int c = ns * 16 + lr;
            #pragma unroll
            for (int ks = 0; ks < 4; ++ks) {
                const int k0 = ks * 32 + lg * 8;
                const bf16x8 bfr = *reinterpret_cast<const bf16x8*>(
                    &Blds[c * 128 + (k0 ^ (lr << 3))]);
                acc[ns] = __builtin_amdgcn_mfma_f32_16x16x32_bf16(afr[ks], bfr, acc[ns], 0, 0, 0);
            }
        }

        // store: C/D layout col = lane&15, row = (lane>>4)*4 + reg
        const int m0 = tile * 64 + wv * 16;
        #pragma unroll
        for (int ns = 0; ns < 16; ++ns) {
            #pragma unroll
            for (int rr = 0; rr < 4; ++rr) {
                const int orow = m0 + lg * 4 + rr;
                if (orow < n_nodes)
                    UV[(size_t)orow * 256 + ns * 16 + lr] = f2bf(acc[ns][rr]);
            }
        }

        #pragma unroll
        for (int i = 0; i < 8; ++i) cur[i] = nxt[i];
        tile = next;
    }
}

// 16 lanes per edge. Lane q owns elements [q*8, q*8+8).
// score[e] = sum_j relu(u[src][j] + v[dst][j] + b1[j]) * W2[j] + b2
__global__ __launch_bounds__(256) void edge_score(
    const int* __restrict__ ei, const unsigned short* __restrict__ UV,
    const float* __restrict__ b1, const float* __restrict__ W2,
    const float* __restrict__ b2, float* __restrict__ out, int n_edges)
{
    const int tid = blockIdx.x * 256 + threadIdx.x;
    const int e = tid >> 4;
    if (e >= n_edges) return;
    const int q = threadIdx.x & 15;

    const int src = ei[e];
    const int dst = ei[n_edges + e];

    const uint4 uraw = *reinterpret_cast<const uint4*>(UV + (size_t)src * 256 + q * 8);
    const uint4 vraw = *reinterpret_cast<const uint4*>(UV + (size_t)dst * 256 + 128 + q * 8);
    const float4 b1a = *reinterpret_cast<const float4*>(b1 + q * 8);
    const float4 b1b = *reinterpret_cast<const float4*>(b1 + q * 8 + 4);
    const float4 w2a = *reinterpret_cast<const float4*>(W2 + q * 8);
    const float4 w2b = *reinterpret_cast<const float4*>(W2 + q * 8 + 4);

    const uint32_t up[4] = { uraw.x, uraw.y, uraw.z, uraw.w };
    const uint32_t vp[4] = { vraw.x, vraw.y, vraw.z, vraw.w };
    const float bb[8] = { b1a.x, b1a.y, b1a.z, b1a.w, b1b.x, b1b.y, b1b.z, b1b.w };
    const float ww[8] = { w2a.x, w2a.y, w2a.z, w2a.w, w2b.x, w2b.y, w2b.z, w2b.w };

    float sum = 0.f;
    #pragma unroll
    for (int p = 0; p < 4; ++p) {
        float h0 = bf_lo(up[p]) + bf_lo(vp[p]) + bb[2 * p];
        float h1 = bf_hi(up[p]) + bf_hi(vp[p]) + bb[2 * p + 1];
        h0 = fmaxf(h0, 0.f);
        h1 = fmaxf(h1, 0.f);
        sum = fmaf(h0, ww[2 * p], sum);
        sum = fmaf(h1, ww[2 * p + 1], sum);
    }

    sum += __shfl_xor(sum, 1, 64);
    sum += __shfl_xor(sum, 2, 64);
    sum += __shfl_xor(sum, 4, 64);
    sum += __shfl_xor(sum, 8, 64);

    if (q == 0) out[e] = sum + b2[0];
}

extern "C" void kernel_launch(void* const* d_in, const int* in_sizes, int n_in,
                              void* d_out, int out_size, void* d_ws, size_t ws_size,
                              hipStream_t stream) {
    const float* z  = (const float*)d_in[0];
    const int*   ei = (const int*)d_in[1];
    const float* W1 = (const float*)d_in[2];
    const float* b1 = (const float*)d_in[3];
    const float* W2 = (const float*)d_in[4];
    const float* b2 = (const float*)d_in[5];
    float* out = (float*)d_out;

    const int n_nodes = in_sizes[0] / HIDDEN;
    const int n_edges = in_sizes[1] / 2;

    unsigned short* UV = (unsigned short*)d_ws;  // [n_nodes][256] bf16

    // Kernel 1: per-node u/v via bf16 MFMA GEMM (64 rows per block-iteration)
    {
        const int n_tiles = (n_nodes + 63) / 64;
        int g1 = n_tiles < 512 ? n_tiles : 512;  // 2 blocks/CU (64 KB LDS each)
        precompute_mfma<<<g1, 256, 0, stream>>>(z, W1, UV, n_nodes, n_tiles);
    }
    // Kernel 2: per-edge score (16 edges per 256-thread block)
    {
        const int blocks = (n_edges * 16 + 255) / 256;
        edge_score<<<blocks, 256, 0, stream>>>(ei, UV, b1, W2, b2, out, n_edges);
    }
}